// Round 8
// baseline (1636.059 us; speedup 1.0000x reference)
//
#include <hip/hip_runtime.h>
#include <hip/hip_bf16.h>
#include <math.h>

#define BDIM 2
#define TSEQ 2048
#define CDIM 1024
#define HNUM 16
#define NROW (BDIM*TSEQ)

typedef __attribute__((ext_vector_type(8))) short bf16x8_t;
typedef __attribute__((ext_vector_type(4))) float f32x4_t;

__device__ inline float bf2f(__hip_bfloat16 h) { return __bfloat162float(h); }

__device__ inline void unpack8(uint4 u, float* f) {
  unsigned v[4] = {u.x, u.y, u.z, u.w};
  #pragma unroll
  for (int i = 0; i < 4; ++i) {
    union { unsigned u2; float f2; } a, b;
    a.u2 = v[i] << 16;
    b.u2 = v[i] & 0xffff0000u;
    f[2*i]   = a.f2;
    f[2*i+1] = b.f2;
  }
}

__global__ __launch_bounds__(256) void zero32_kernel(float* p, int n) {
  int i = blockIdx.x * 256 + threadIdx.x;
  if (i < n) p[i] = 0.f;
}

// fp32 -> bf16 weight conversion
__global__ __launch_bounds__(256) void convert_kernel(const float* __restrict__ src,
    __hip_bfloat16* __restrict__ dst, int n)
{
  const int stride = gridDim.x * 256 * 4;
  for (int i = (blockIdx.x * 256 + threadIdx.x) * 4; i < n; i += stride) {
    #pragma unroll
    for (int j = 0; j < 4; ++j) dst[i+j] = __float2bfloat16(src[i+j]);
  }
}

__device__ inline void blk_reduce3(float& a, float& b, float& c, float* red) {
  const int lane = threadIdx.x & 63, wv = threadIdx.x >> 6;
  #pragma unroll
  for (int off = 32; off; off >>= 1) {
    a += __shfl_xor(a, off); b += __shfl_xor(b, off); c += __shfl_xor(c, off);
  }
  if (lane == 0) { red[wv] = a; red[4+wv] = b; red[8+wv] = c; }
  __syncthreads();
  a = red[0]+red[1]+red[2]+red[3];
  b = red[4]+red[5]+red[6]+red[7];
  c = red[8]+red[9]+red[10]+red[11];
}

// ---------------- LayerNorm: fp32 in, fp32 w/b, bf16 out ----------------
__global__ __launch_bounds__(256) void ln_kernel(const float* __restrict__ x,
    const float* __restrict__ w, const float* __restrict__ b,
    __hip_bfloat16* __restrict__ out)
{
  const int row = blockIdx.x;
  const size_t base = (size_t)row * CDIM;
  const int lane = threadIdx.x & 63, wv = threadIdx.x >> 6;
  float v[4]; float s = 0.f, s2 = 0.f;
  #pragma unroll
  for (int k = 0; k < 4; ++k) {
    int d = threadIdx.x + k*256;
    float xe = x[base + d];
    v[k] = xe; s += xe; s2 += xe*xe;
  }
  __shared__ float red[8];
  #pragma unroll
  for (int off = 32; off; off >>= 1) { s += __shfl_xor(s, off); s2 += __shfl_xor(s2, off); }
  if (lane == 0) { red[wv] = s; red[4+wv] = s2; }
  __syncthreads();
  s  = red[0]+red[1]+red[2]+red[3];
  s2 = red[4]+red[5]+red[6]+red[7];
  float mu = s * (1.0f/CDIM);
  float var = s2 * (1.0f/CDIM) - mu*mu;
  float rstd = rsqrtf(fmaxf(var, 0.f) + 1e-5f);
  #pragma unroll
  for (int k = 0; k < 4; ++k) {
    int d = threadIdx.x + k*256;
    out[base + d] = __float2bfloat16((v[k]-mu)*rstd*w[d] + b[d]);
  }
}

// ---------------- scal1: xt[r] = P*xn[r] + Q*xn[r-1]  (verified r5/r6) ----------------
__global__ __launch_bounds__(256) void scal1_kernel(const __hip_bfloat16* __restrict__ xn,
                                                    float2* __restrict__ pq)
{
  const int row = blockIdx.x;
  const bool has = (row & (TSEQ-1)) != 0;
  const __hip_bfloat16* u  = xn + (size_t)row * CDIM;
  const __hip_bfloat16* xp = xn + (size_t)(has ? row-1 : row) * CDIM;
  float sxx = 0.f, suu = 0.f, sxu = 0.f;
  #pragma unroll
  for (int k = 0; k < 4; ++k) {
    int d = threadIdx.x + k*256;
    float ue = bf2f(u[d]);
    float xe = has ? bf2f(xp[d]) : 0.f;
    sxx += xe*xe; suu += ue*ue; sxu += xe*ue;
  }
  __shared__ float red[12];
  blk_reduce3(sxx, suu, sxu, red);
  float den = 1.f - 2.f*sxu + sxx*suu;
  float inv = 1.f / fmaxf(den, 1e-30f);
  float cb = 1.f - sxx;
  float ca = 1.f - 2.f*sxu + suu;
  float mm = inv*inv*(cb*cb*suu - 2.f*ca*cb*sxu + ca*ca*sxx);
  float mn = sqrtf(fmaxf(mm, 0.f));
  float arg = fminf(sqrtf(mn), 0.999f);
  float fac = (1.f + sxx) * atanhf(arg) / fmaxf(mn, 1e-30f);
  if (threadIdx.x == 0)
    pq[row] = make_float2(fac*cb*inv, has ? -fac*ca*inv : 0.f);
}

// ---------------- scal2: e[r] = S*y[r] + R*xn[r-1]  (verified r5/r6) ----------------
__global__ __launch_bounds__(256) void scal2_kernel(const __hip_bfloat16* __restrict__ xn,
                                                    const __hip_bfloat16* __restrict__ y,
                                                    float2* __restrict__ sr)
{
  const int row = blockIdx.x;
  const bool has = (row & (TSEQ-1)) != 0;
  const __hip_bfloat16* xp = xn + (size_t)(has ? row-1 : row) * CDIM;
  const __hip_bfloat16* vr = y + (size_t)row * CDIM;
  float sxx = 0.f, svv = 0.f, sxv = 0.f;
  #pragma unroll
  for (int k = 0; k < 4; ++k) {
    int d = threadIdx.x + k*256;
    float ve = bf2f(vr[d]);
    float xe = has ? bf2f(xp[d]) : 0.f;
    sxx += xe*xe; svv += ve*ve; sxv += xe*ve;
  }
  __shared__ float red[12];
  blk_reduce3(sxx, svv, sxv, red);
  float lam = 2.f / (1.f + sxx);
  float vn  = sqrtf(fmaxf(svv, 1e-30f));
  float th  = tanhf(vn * sqrtf(0.5f*lam));
  float s   = th / vn;
  float yn2 = th*th;
  float ip  = s * sxv;
  float den = 1.f + 2.f*ip + sxx*yn2;
  float inv = 1.f / fmaxf(den, 1e-30f);
  if (threadIdx.x == 0)
    sr[row] = make_float2((1.f - sxx)*s*inv, has ? (1.f + 2.f*ip + yn2)*inv : 0.f);
}

// ---------------- MFMA GEMM (bf16 A/B, fp32 bias/res) ----------------
// FUSEA: A_eff[r][k] = scal[r].x * A[r][k] + scal[r].y * Aprev[prevrow(r)][k]
// MODE 0: bf16 out = acc + bias
// MODE 1: f32  out = acc + bias + res
// MODE 2: bf16 out = gelu(acc + bias)
// MODE 4: f32  out = acc + bias + res   (in-place ok)
// MODE 5: f32  out = acc + res          (in-place ok)
// MODE 7: f32  out = acc + res
template<int MODE, bool FUSEA>
__global__ __launch_bounds__(256) void gemm_kernel(
    const __hip_bfloat16* __restrict__ A,
    const __hip_bfloat16* __restrict__ Aprev,
    const float2* __restrict__ scal,
    const __hip_bfloat16* __restrict__ B, int ldb,
    const float* __restrict__ bias,
    const float* __restrict__ res,
    void* __restrict__ outp,
    int M, int N, int K)
{
  __shared__ __align__(16) __hip_bfloat16 Asl[64*40];
  __shared__ __align__(16) __hip_bfloat16 Bsl[64*40];
  const int bm = blockIdx.x, bn = blockIdx.y;
  const int tid = threadIdx.x;
  const int lane = tid & 63, wv = tid >> 6;
  const int wm = (wv >> 1) * 32, wn = (wv & 1) * 32;
  f32x4_t acc00 = {0.f,0.f,0.f,0.f}, acc01 = {0.f,0.f,0.f,0.f};
  f32x4_t acc10 = {0.f,0.f,0.f,0.f}, acc11 = {0.f,0.f,0.f,0.f};
  const int ar = tid >> 2, aseg = (tid & 3) * 8;
  const int br = tid >> 3, bseg = (tid & 7) * 8;
  const int fr = lane & 15, q8 = (lane >> 4) * 8;

  const int gr = bm*64 + ar;
  float2 sc = make_float2(0.f, 0.f);
  int prow = gr;
  if (FUSEA) {
    sc = scal[gr];
    prow = ((gr & (TSEQ-1)) == 0) ? gr : gr - 1;
  }

  for (int k0 = 0; k0 < K; k0 += 32) {
    uint4 av;
    if (FUSEA) {
      uint4 pu = *(const uint4*)(A + (size_t)gr*K + k0 + aseg);
      uint4 qu = *(const uint4*)(Aprev + (size_t)prow*K + k0 + aseg);
      float pf[8], qf[8];
      unpack8(pu, pf); unpack8(qu, qf);
      union { uint4 u; __hip_bfloat16 h[8]; } cv;
      #pragma unroll
      for (int j = 0; j < 8; ++j) cv.h[j] = __float2bfloat16(sc.x*pf[j] + sc.y*qf[j]);
      av = cv.u;
    } else {
      av = *(const uint4*)(A + (size_t)gr*K + k0 + aseg);
    }
    uint4 bv = *(const uint4*)(B + (size_t)(k0 + br)*ldb + bn*64 + bseg);
    __syncthreads();
    *(uint4*)(&Asl[ar*40 + aseg]) = av;
    union { uint4 u; __hip_bfloat16 hh[8]; } bu; bu.u = bv;
    #pragma unroll
    for (int e = 0; e < 8; ++e) Bsl[(bseg + e)*40 + br] = bu.hh[e];
    __syncthreads();
    bf16x8_t a0 = *(const bf16x8_t*)(&Asl[(wm + fr)*40 + q8]);
    bf16x8_t a1 = *(const bf16x8_t*)(&Asl[(wm + 16 + fr)*40 + q8]);
    bf16x8_t b0 = *(const bf16x8_t*)(&Bsl[(wn + fr)*40 + q8]);
    bf16x8_t b1 = *(const bf16x8_t*)(&Bsl[(wn + 16 + fr)*40 + q8]);
    acc00 = __builtin_amdgcn_mfma_f32_16x16x32_bf16(a0, b0, acc00, 0, 0, 0);
    acc01 = __builtin_amdgcn_mfma_f32_16x16x32_bf16(a0, b1, acc01, 0, 0, 0);
    acc10 = __builtin_amdgcn_mfma_f32_16x16x32_bf16(a1, b0, acc10, 0, 0, 0);
    acc11 = __builtin_amdgcn_mfma_f32_16x16x32_bf16(a1, b1, acc11, 0, 0, 0);
  }

  const int colq = lane & 15, quad = lane >> 4;
  f32x4_t accs[2][2] = {{acc00, acc01}, {acc10, acc11}};
  #pragma unroll
  for (int tm = 0; tm < 2; ++tm)
  #pragma unroll
  for (int tn = 0; tn < 2; ++tn)
  #pragma unroll
  for (int r = 0; r < 4; ++r) {
    int row = bm*64 + wm + tm*16 + quad*4 + r;
    int col = bn*64 + wn + tn*16 + colq;
    size_t idx = (size_t)row * N + col;
    float v = accs[tm][tn][r];
    if (MODE == 0) {
      v += bias[col];
      ((__hip_bfloat16*)outp)[idx] = __float2bfloat16(v);
    } else if (MODE == 1) {
      v += bias[col] + res[idx];
      ((float*)outp)[idx] = v;
    } else if (MODE == 2) {
      v += bias[col];
      v = 0.5f * v * (1.0f + erff(v * 0.70710678118654752f));
      ((__hip_bfloat16*)outp)[idx] = __float2bfloat16(v);
    } else if (MODE == 4) {
      v += bias[col] + res[idx];
      ((float*)outp)[idx] = v;
    } else if (MODE == 5) {
      v += res[idx];
      ((float*)outp)[idx] = v;
    } else {
      v += res[idx];
      ((float*)outp)[idx] = v;
    }
  }
}

// ---------------- attention (verified r5/r6 vs naive softmax) ----------------
__global__ __launch_bounds__(256) void attn_kernel(const __hip_bfloat16* __restrict__ qkv,
                                                   __hip_bfloat16* __restrict__ y)
{
  const int qt = blockIdx.x;
  const int b  = blockIdx.y >> 4;
  const int h  = blockIdx.y & 15;
  const int tid = threadIdx.x;
  const int lane = tid & 63;
  const int wv = tid >> 6;
  const int t0 = qt * 16;

  __shared__ __align__(16) float Kt[64*76];
  __shared__ __align__(16) float VtT[64*76];
  __shared__ __align__(16) float qs[16*68];
  __shared__ __align__(16) float ps[16*68];

  #pragma unroll
  for (int e = 0; e < 4; ++e) {
    int idx = tid + e*256;
    int qi = idx >> 6, d = idx & 63;
    qs[qi*68 + d] = 0.125f * bf2f(qkv[((size_t)(b*TSEQ + t0 + qi))*(3*CDIM) + h*64 + d]);
  }

  float ov[4] = {0.f,0.f,0.f,0.f};
  float mr[4] = {-1e30f,-1e30f,-1e30f,-1e30f};
  float lr[4] = {0.f,0.f,0.f,0.f};
  const int tqb = t0 + wv*4;
  const int nchunk = (t0 + 15)/64 + 1;
  const int jr = tid >> 2;
  const int sg = (tid & 3) * 16;

  for (int c = 0; c < nchunk; ++c) {
    __syncthreads();
    {
      size_t base = ((size_t)(b*TSEQ + c*64 + jr))*(3*CDIM) + h*64 + sg;
      const uint4* kp = (const uint4*)(qkv + base + CDIM);
      const uint4* vp = (const uint4*)(qkv + base + 2*CDIM);
      uint4 ku0 = kp[0], ku1 = kp[1];
      uint4 vu0 = vp[0], vu1 = vp[1];
      float kf[16], vf[16];
      unpack8(ku0, kf); unpack8(ku1, kf+8);
      unpack8(vu0, vf); unpack8(vu1, vf+8);
      #pragma unroll
      for (int i = 0; i < 4; ++i)
        *(float4*)(&Kt[jr*76 + sg + i*4]) = make_float4(kf[4*i], kf[4*i+1], kf[4*i+2], kf[4*i+3]);
      #pragma unroll
      for (int i = 0; i < 16; ++i) VtT[(sg + i)*76 + jr] = vf[i];
    }
    __syncthreads();

    float sv[4] = {0.f,0.f,0.f,0.f};
    {
      const float4* Kr = (const float4*)(Kt + lane*76);
      const float4* Q0 = (const float4*)(qs + (wv*4 + 0)*68);
      const float4* Q1 = (const float4*)(qs + (wv*4 + 1)*68);
      const float4* Q2 = (const float4*)(qs + (wv*4 + 2)*68);
      const float4* Q3 = (const float4*)(qs + (wv*4 + 3)*68);
      #pragma unroll
      for (int d4 = 0; d4 < 16; ++d4) {
        float4 kv = Kr[d4];
        float4 a = Q0[d4]; sv[0] += kv.x*a.x + kv.y*a.y + kv.z*a.z + kv.w*a.w;
        float4 b1 = Q1[d4]; sv[1] += kv.x*b1.x + kv.y*b1.y + kv.z*b1.z + kv.w*b1.w;
        float4 c1 = Q2[d4]; sv[2] += kv.x*c1.x + kv.y*c1.y + kv.z*c1.z + kv.w*c1.w;
        float4 dq = Q3[d4]; sv[3] += kv.x*dq.x + kv.y*dq.y + kv.z*dq.z + kv.w*dq.w;
      }
    }
    const int jg = c*64 + lane;
    float alpha[4] = {1.f,1.f,1.f,1.f};
    #pragma unroll
    for (int q = 0; q < 4; ++q) {
      const int tq = tqb + q;
      float s = sv[q];
      if (jg > tq) s = -1e30f;
      float cmax = s;
      #pragma unroll
      for (int off = 32; off; off >>= 1) cmax = fmaxf(cmax, __shfl_xor(cmax, off));
      float mnew = fmaxf(mr[q], cmax);
      alpha[q] = expf(mr[q] - mnew);
      float p = expf(s - mnew);
      float psum = p;
      #pragma unroll
      for (int off = 32; off; off >>= 1) psum += __shfl_xor(psum, off);
      lr[q] = lr[q]*alpha[q] + psum;
      mr[q] = mnew;
      ps[(wv*4 + q)*68 + lane] = p;
    }
    float av[4] = {0.f,0.f,0.f,0.f};
    {
      const float4* Vr = (const float4*)(VtT + lane*76);
      const float4* P0 = (const float4*)(ps + (wv*4 + 0)*68);
      const float4* P1 = (const float4*)(ps + (wv*4 + 1)*68);
      const float4* P2 = (const float4*)(ps + (wv*4 + 2)*68);
      const float4* P3 = (const float4*)(ps + (wv*4 + 3)*68);
      #pragma unroll
      for (int j4 = 0; j4 < 16; ++j4) {
        float4 vvv = Vr[j4];
        float4 a = P0[j4]; av[0] += vvv.x*a.x + vvv.y*a.y + vvv.z*a.z + vvv.w*a.w;
        float4 b1 = P1[j4]; av[1] += vvv.x*b1.x + vvv.y*b1.y + vvv.z*b1.z + vvv.w*b1.w;
        float4 c1 = P2[j4]; av[2] += vvv.x*c1.x + vvv.y*c1.y + vvv.z*c1.z + vvv.w*c1.w;
        float4 dq = P3[j4]; av[3] += vvv.x*dq.x + vvv.y*dq.y + vvv.z*dq.z + vvv.w*dq.w;
      }
    }
    #pragma unroll
    for (int q = 0; q < 4; ++q) ov[q] = ov[q]*alpha[q] + av[q];
  }

  #pragma unroll
  for (int q = 0; q < 4; ++q) {
    y[((size_t)(b*TSEQ + tqb + q))*CDIM + h*64 + lane] = __float2bfloat16(ov[q] / lr[q]);
  }
}

// ================= launch =================
extern "C" void kernel_launch(void* const* d_in, const int* in_sizes, int n_in,
                              void* d_out, int out_size, void* d_ws, size_t ws_size,
                              hipStream_t stream)
{
  float* out = (float*)d_out;                     // OUTPUT IS FP32 (reference returns jnp.float32)
  __hip_bfloat16* ybuf = (__hip_bfloat16*)d_out;  // first 8MB used as bf16 scratch for attention y
  char* ws = (char*)d_ws;
  const size_t KB = 1024, MB = 1024*1024;

  if (ws_size < 49*MB) {
    zero32_kernel<<<(out_size + 255)/256, 256, 0, stream>>>(out, out_size);
    return;
  }

  const float* x      = (const float*)d_in[0];
  const float* ln1w   = (const float*)d_in[1];
  const float* ln1b   = (const float*)d_in[2];
  const float* Wattn  = (const float*)d_in[3];
  const float* battn  = (const float*)d_in[4];
  const float* Waproj = (const float*)d_in[5];
  const float* baproj = (const float*)d_in[6];
  const float* ln2w   = (const float*)d_in[7];
  const float* ln2b   = (const float*)d_in[8];
  const float* Wfc    = (const float*)d_in[9];
  const float* bfc    = (const float*)d_in[10];
  const float* Wmproj = (const float*)d_in[11];
  const float* bmproj = (const float*)d_in[12];

  // Workspace (<= 48.1 MB):
  // [0,32K): pq   [32K,64K): sr
  // [64K, 64K+8M):        xn bf16 -> hbuf bf16 (after LN2)
  // [64K+8M, 64K+32M):    qkv bf16 (24M) -> x2 fp32 (16M) + gbuf bf16 (8M)
  // [64K+32M, 64K+48M):   cregion: phase1 cWattn(6M)+cWaproj(2M); phase2 cWfc(8M)+cWm(8M)
  float2* pq           = (float2*)(ws);
  float2* sr           = (float2*)(ws + 32*KB);
  __hip_bfloat16* xn   = (__hip_bfloat16*)(ws + 64*KB);
  char* big            = ws + 64*KB + 8*MB;
  __hip_bfloat16* qkv  = (__hip_bfloat16*)big;
  float* x2            = (float*)big;
  __hip_bfloat16* gbuf = (__hip_bfloat16*)(big + 16*MB);
  __hip_bfloat16* hbuf = xn;
  char* creg           = ws + 64*KB + 32*MB;
  __hip_bfloat16* cWattn  = (__hip_bfloat16*)creg;             // 6 MB
  __hip_bfloat16* cWaproj = (__hip_bfloat16*)(creg + 6*MB);    // 2 MB
  __hip_bfloat16* cWfc    = (__hip_bfloat16*)creg;             // 8 MB (phase 2)
  __hip_bfloat16* cWm     = (__hip_bfloat16*)(creg + 8*MB);    // 8 MB (phase 2)

  // phase-1 weight conversions
  convert_kernel<<<1024, 256, 0, stream>>>(Wattn,  cWattn, 3145728);
  convert_kernel<<<512,  256, 0, stream>>>(Waproj, cWaproj, 1048576);

  // 1. xn = LN1(x)
  ln_kernel<<<NROW, 256, 0, stream>>>(x, ln1w, ln1b, xn);
  // 2. logmap coefficients
  scal1_kernel<<<NROW, 256, 0, stream>>>(xn, pq);
  // 3. qkv = xt @ W_attn + b_attn  (fused A)
  gemm_kernel<0, true><<<dim3(64, 48), 256, 0, stream>>>(
      xn, xn, pq, cWattn, 3072, battn, nullptr, qkv, NROW, 3072, CDIM);
  // 4. attention -> ybuf (bf16 scratch inside d_out)
  attn_kernel<<<dim3(TSEQ/16, BDIM*HNUM), 256, 0, stream>>>(qkv, ybuf);
  // 5. expmap coefficients
  scal2_kernel<<<NROW, 256, 0, stream>>>(xn, ybuf, sr);
  // 6. x2 = x + e @ W_aproj + b_aproj   (fused A; exact fp32 x residual)
  gemm_kernel<1, true><<<dim3(64, 16), 256, 0, stream>>>(
      ybuf, xn, sr, cWaproj, 1024, baproj, x, x2, NROW, 1024, CDIM);
  // phase-2 conversions (Wattn/Waproj dead)
  convert_kernel<<<1024, 256, 0, stream>>>(Wfc,    cWfc, 4194304);
  convert_kernel<<<1024, 256, 0, stream>>>(Wmproj, cWm,  4194304);
  // 7. hbuf = LN2(x2)
  ln_kernel<<<NROW, 256, 0, stream>>>(x2, ln2w, ln2b, hbuf);
  // 8/9. MLP in 4 hidden-chunks of 1024; fp32 accumulate into x2; final -> fp32 d_out
  for (int c = 0; c < 4; ++c) {
    gemm_kernel<2, false><<<dim3(64, 16), 256, 0, stream>>>(
        hbuf, nullptr, nullptr, cWfc + 1024*c, 4096, bfc + 1024*c, nullptr, gbuf,
        NROW, 1024, CDIM);
    const __hip_bfloat16* Bc = cWm + (size_t)c*1024*1024;
    if (c == 0) {
      gemm_kernel<4, false><<<dim3(64, 16), 256, 0, stream>>>(
          gbuf, nullptr, nullptr, Bc, 1024, bmproj, x2, x2, NROW, 1024, 1024);
    } else if (c < 3) {
      gemm_kernel<5, false><<<dim3(64, 16), 256, 0, stream>>>(
          gbuf, nullptr, nullptr, Bc, 1024, nullptr, x2, x2, NROW, 1024, 1024);
    } else {
      gemm_kernel<7, false><<<dim3(64, 16), 256, 0, stream>>>(
          gbuf, nullptr, nullptr, Bc, 1024, nullptr, x2, out, NROW, 1024, 1024);
    }
  }
}